// Round 14
// baseline (1290.766 us; speedup 1.0000x reference)
//
#include <hip/hip_runtime.h>

#define NN 8192
#define FI 256
#define FO 128
#define GAT_ALPHA 0.2f

// ===== PROBE ROUND 2: every kernel rep-looped past the ~155us fill duration =====
#define K1_REPS 24
#define K2_REPS 8
#define K3_REPS 48
#define K4_REPS 8
#define K5_REPS 48

typedef _Float16 f16x8 __attribute__((ext_vector_type(8)));
typedef _Float16 f16x2 __attribute__((ext_vector_type(2)));
typedef float f32x4 __attribute__((ext_vector_type(4)));
typedef unsigned char uchar;
typedef unsigned int uint32;

// ---------------------------------------------------------------------------
// K1 (fused k1b), rep-looped. All stores idempotent.
// ---------------------------------------------------------------------------
__global__ __launch_bounds__(256) void k1_wh(const float* __restrict__ h,
                                             const float* __restrict__ W,
                                             const float* __restrict__ bias,
                                             const float* __restrict__ a,
                                             float* __restrict__ Wh,
                                             float4* __restrict__ r4,
                                             float4* __restrict__ c4,
                                             float2* __restrict__ r2,
                                             _Float16* __restrict__ ey16,
                                             _Float16* __restrict__ ez16,
                                             float* __restrict__ s2x,
                                             float* __restrict__ corr) {
  __shared__ float hs[32][FI + 1];
  __shared__ float wt[32][FO];
  const int t = threadIdx.x;
  const int j0 = blockIdx.x * 32;
  if (blockIdx.x == 0 && t < FO) corr[t] = 0.f;
#pragma unroll 1
  for (int rep = 0; rep < K1_REPS; ++rep) {
    __syncthreads();
    asm volatile("" ::: "memory");
    {
      const int row = t >> 3, c0 = (t & 7) * 32;
      const float* src = h + (size_t)(j0 + row) * FI + c0;
#pragma unroll
      for (int e = 0; e < 8; ++e) {
        float4 v = *(const float4*)(src + 4 * e);
        hs[row][c0 + 4 * e + 0] = v.x;
        hs[row][c0 + 4 * e + 1] = v.y;
        hs[row][c0 + 4 * e + 2] = v.z;
        hs[row][c0 + 4 * e + 3] = v.w;
      }
    }
    const int f4 = (t & 31) * 4;
    const int r0 = (t >> 5) * 4;
    float acc[4][4];
#pragma unroll
    for (int r = 0; r < 4; ++r)
#pragma unroll
      for (int e = 0; e < 4; ++e) acc[r][e] = 0.f;

    for (int kc = 0; kc < FI; kc += 32) {
      __syncthreads();
      {
        const int f = t >> 1, kb = (t & 1) * 16;
        const float* wsrc = W + (size_t)f * FI + kc + kb;
#pragma unroll
        for (int e = 0; e < 16; ++e) wt[kb + e][f] = wsrc[e];
      }
      __syncthreads();
#pragma unroll
      for (int k = 0; k < 32; ++k) {
        const float4 wv = *(const float4*)&wt[k][f4];
        float hv[4];
#pragma unroll
        for (int r = 0; r < 4; ++r) hv[r] = hs[r0 + r][kc + k];
#pragma unroll
        for (int r = 0; r < 4; ++r) {
          acc[r][0] += hv[r] * wv.x;
          acc[r][1] += hv[r] * wv.y;
          acc[r][2] += hv[r] * wv.z;
          acc[r][3] += hv[r] * wv.w;
        }
      }
    }
    const float4 bv = *(const float4*)&bias[f4];
    const float4 a1v = *(const float4*)&a[f4];
    const float4 a2v = *(const float4*)&a[FO + f4];
    float s1p[4], s2p[4];
#pragma unroll
    for (int r = 0; r < 4; ++r) {
      float4 o;
      o.x = acc[r][0] + bv.x;
      o.y = acc[r][1] + bv.y;
      o.z = acc[r][2] + bv.z;
      o.w = acc[r][3] + bv.w;
      *(float4*)&Wh[(size_t)(j0 + r0 + r) * FO + f4] = o;
      s1p[r] = o.x * a1v.x + o.y * a1v.y + o.z * a1v.z + o.w * a1v.w;
      s2p[r] = o.x * a2v.x + o.y * a2v.y + o.z * a2v.z + o.w * a2v.w;
    }
#pragma unroll
    for (int m = 16; m >= 1; m >>= 1) {
#pragma unroll
      for (int r = 0; r < 4; ++r) {
        s1p[r] += __shfl_xor(s1p[r], m);
        s2p[r] += __shfl_xor(s2p[r], m);
      }
    }
    if ((t & 31) == 0) {
#pragma unroll
      for (int r = 0; r < 4; ++r) {
        const int j = j0 + r0 + r;
        const float s1 = s1p[r], s2 = s2p[r];
        const float e1 = expf(s1), e1a = expf(GAT_ALPHA * s1);
        const float e2 = expf(s2), e2a = expf(GAT_ALPHA * s2);
        float4 rv; rv.x = s1; rv.y = e1; rv.z = e1a; rv.w = 0.f;
        float4 cv; cv.x = s2; cv.y = e2; cv.z = e2a; cv.w = 0.f;
        r4[j] = rv;
        c4[j] = cv;
        r2[j] = make_float2(e1, e1a);
        ey16[j] = (_Float16)e2;
        ez16[j] = (_Float16)e2a;
        s2x[j] = s2;
      }
    }
  }
}

// ---------------------------------------------------------------------------
// K2, rep-looped (R8-validated pattern).
// ---------------------------------------------------------------------------
__global__ __launch_bounds__(256) void k2_stats(const int* __restrict__ adj,
                                                const float4* __restrict__ r4,
                                                const float* __restrict__ s2x,
                                                uchar* __restrict__ bitsB,
                                                float2* __restrict__ zpart) {
  __shared__ float4 rs[64];
  const int t = threadIdx.x;
  const int jc = blockIdx.x & 3;
  const int ic = blockIdx.x >> 2;
  const int i0 = ic * 64;
  const int j0 = jc * 2048 + t * 8;
  if (t < 64) rs[t] = r4[i0 + t];
  const float4 ca = *(const float4*)(s2x + j0);
  const float4 cb = *(const float4*)(s2x + j0 + 4);
  const float cx[8] = {ca.x, ca.y, ca.z, ca.w, cb.x, cb.y, cb.z, cb.w};
  float accP[8], accN[8];
  __syncthreads();
  const int4* ap = (const int4*)(adj + (size_t)i0 * NN + j0);
  uchar* bp = bitsB + (size_t)i0 * (NN / 8) + jc * 256 + t;
#pragma unroll 1
  for (int rep = 0; rep < K2_REPS; ++rep) {
    asm volatile("" ::: "memory");
#pragma unroll
    for (int e = 0; e < 8; ++e) { accP[e] = 0.f; accN[e] = 0.f; }
    for (int ir = 0; ir < 64; ir += 8) {
      int4 av[8][2];
#pragma unroll
      for (int u = 0; u < 8; ++u) {
        av[u][0] = ap[(size_t)(ir + u) * (NN / 4)];
        av[u][1] = ap[(size_t)(ir + u) * (NN / 4) + 1];
      }
#pragma unroll
      for (int u = 0; u < 8; ++u) {
        const float4 ri = rs[ir + u];
        const int aa[8] = {av[u][0].x, av[u][0].y, av[u][0].z, av[u][0].w,
                           av[u][1].x, av[u][1].y, av[u][1].z, av[u][1].w};
        uint32 byte = 0;
#pragma unroll
        for (int e = 0; e < 8; ++e) {
          const bool act = aa[e] > 0;
          byte |= act ? (1u << e) : 0u;
          const bool pos = (ri.x + cx[e]) >= 0.f;
          accP[e] += (act && pos) ? ri.y : 0.f;
          accN[e] += (act && !pos) ? ri.z : 0.f;
        }
        bp[(size_t)(ir + u) * (NN / 8)] = (uchar)byte;
      }
    }
    asm volatile("" ::
                     "v"(accP[0]), "v"(accP[1]), "v"(accP[2]), "v"(accP[3]),
                     "v"(accP[4]), "v"(accP[5]), "v"(accP[6]), "v"(accP[7]),
                     "v"(accN[0]), "v"(accN[1]), "v"(accN[2]), "v"(accN[3]),
                     "v"(accN[4]), "v"(accN[5]), "v"(accN[6]), "v"(accN[7]));
  }
  float2* zp = zpart + (size_t)ic * NN + j0;
#pragma unroll
  for (int e = 0; e < 8; ++e) zp[e] = make_float2(accP[e], accN[e]);
}

// ---------------------------------------------------------------------------
// K3 (full), rep-looped; corr atomic only on rep 0.
// ---------------------------------------------------------------------------
__global__ __launch_bounds__(256) void k3_scale(const float* __restrict__ Wh,
                                                const float4* __restrict__ c4,
                                                const float2* __restrict__ zpart,
                                                _Float16* __restrict__ Wfrag,
                                                float* __restrict__ corr) {
  __shared__ float rz[64];
  __shared__ int emp[64];
  __shared__ float2 psum[256];
  __shared__ __align__(16) _Float16 tile[FO * 64];
  const int t = threadIdx.x;
  const int j0 = blockIdx.x * 64;
#pragma unroll 1
  for (int rep = 0; rep < K3_REPS; ++rep) {
    __syncthreads();
    asm volatile("" ::: "memory");
    {
      const int jl = t & 63, q = t >> 6;
      float p = 0.f, n = 0.f;
      for (int ic = q * 32; ic < q * 32 + 32; ++ic) {
        const float2 z = zpart[(size_t)ic * NN + j0 + jl];
        p += z.x;
        n += z.y;
      }
      psum[t] = make_float2(p, n);
    }
    __syncthreads();
    if (t < 64) {
      const float p = psum[t].x + psum[64 + t].x + psum[128 + t].x + psum[192 + t].x;
      const float n = psum[t].y + psum[64 + t].y + psum[128 + t].y + psum[192 + t].y;
      const float4 cj = c4[j0 + t];
      const float Z = cj.y * p + cj.z * n;
      rz[t] = (Z > 0.f) ? 1.f / Z : 0.f;
      emp[t] = (Z > 0.f) ? 0 : 1;
    }
    __syncthreads();
    const int f = t & 127, half = t >> 7;
    const unsigned swf = (unsigned)((f & 7) << 4);
    for (int r = half; r < 64; r += 2) {
      const float v = Wh[(size_t)(j0 + r) * FO + f];
      *(_Float16*)((char*)tile + f * 128 + (((unsigned)(r * 2)) ^ swf)) =
          (_Float16)(v * rz[r]);
      if (emp[r] && rep == 0) atomicAdd(&corr[f], v * (1.f / 8192.f));
    }
    __syncthreads();
#pragma unroll
    for (int q = 0; q < 4; ++q) {
      const int G = t + 256 * q;
      const int kcfb = G >> 6, gl = G & 63;
      const int kc = kcfb >> 3, fb = kcfb & 7;
      const int gf = fb * 16 + (gl & 15);
      const int jloc = kc * 32 + (gl >> 4) * 8;
      const f16x8 v = *(const f16x8*)((const char*)tile + gf * 128 +
                                      (((unsigned)(jloc * 2)) ^ ((unsigned)((gf & 7) << 4))));
      ((f16x8*)Wfrag)[(size_t)(((j0 >> 5) + kc) * 8 + fb) * 64 + gl] = v;
    }
  }
}

// ---------------------------------------------------------------------------
// K4 (R11 champion structure), rep-looped with acc reset + keep-alive.
// ---------------------------------------------------------------------------
#define BARRIER_LDS()                                          \
  do {                                                         \
    __builtin_amdgcn_sched_barrier(0);                         \
    asm volatile("s_waitcnt lgkmcnt(0)" ::: "memory");         \
    __builtin_amdgcn_s_barrier();                              \
    __builtin_amdgcn_sched_barrier(0);                         \
  } while (0)

__global__ __launch_bounds__(256) void k4_main(const uchar* __restrict__ bitsB,
                                               const float2* __restrict__ r2,
                                               const _Float16* __restrict__ ey16,
                                               const _Float16* __restrict__ ez16,
                                               const _Float16* __restrict__ Wfrag,
                                               float* __restrict__ part) {
  __shared__ __align__(16) _Float16 P[2][32 * 64];
  __shared__ uint32 lut[256][4];
  const int t = threadIdx.x;
  const int rowtile = blockIdx.x >> 2;
  const int kq = blockIdx.x & 3;
  const int rowbase = rowtile * 32;
  const int koff = kq * 2048;

  {
#pragma unroll
    for (int p = 0; p < 4; ++p) {
      const uint32 lo = ((t >> (2 * p)) & 1) ? 0x0000FFFFu : 0u;
      const uint32 hi = ((t >> (2 * p + 1)) & 1) ? 0xFFFF0000u : 0u;
      lut[t][p] = lo | hi;
    }
  }

  const int pr = t >> 3, jq = t & 7;
  const float2 rr = r2[rowbase + pr];
  const f16x2 rx2 = {(_Float16)rr.x, (_Float16)rr.x};
  const f16x2 ry2 = {(_Float16)rr.y, (_Float16)rr.y};
  const uchar* bp = bitsB + (size_t)(rowbase + pr) * (NN / 8) + (koff >> 3) + jq;
  const _Float16* eyp = ey16 + koff + jq * 8;
  const _Float16* ezp = ez16 + koff + jq * 8;
  char* const pdst0 = (char*)&P[0][0] + pr * 128 + (((unsigned)(jq * 16)) ^ ((unsigned)((pr & 7) << 4)));
  char* const pdst1 = (char*)&P[1][0] + pr * 128 + (((unsigned)(jq * 16)) ^ ((unsigned)((pr & 7) << 4)));

  const int lane = t & 63, wc = t >> 6;
  const int kgrp = lane >> 4, l15 = lane & 15;
  const unsigned asw = (unsigned)((l15 & 7) << 4);
  const int ar0 = l15 * 128;
  const int ar1 = ar0 + 16 * 128;

  f32x4 acc00, acc01, acc10, acc11;

  uchar mb0, mb1;
  uint4 ey0, ez0, ey1, ez1;
  f16x8 B000, B001, B010, B011, B100, B101, B110, B111;

#define LOADALL(S, MB, EY, EZ, Bq00, Bq01, Bq10, Bq11)                              \
  do {                                                                              \
    MB = bp[(S) * 8];                                                               \
    EY = *(const uint4*)(eyp + (S) * 64);                                           \
    EZ = *(const uint4*)(ezp + (S) * 64);                                           \
    const _Float16* _b = Wfrag + ((size_t)((kq * 64 + (S) * 2) * 8 + wc * 2) * 64 + lane) * 8; \
    Bq00 = *(const f16x8*)(_b);                                                     \
    Bq01 = *(const f16x8*)(_b + 512);                                               \
    Bq10 = *(const f16x8*)(_b + 4096);                                              \
    Bq11 = *(const f16x8*)(_b + 4096 + 512);                                        \
  } while (0)

#define PGEN(DST, MB, EY, EZ)                                                        \
  do {                                                                               \
    const uint4 _m = *(const uint4*)(&lut[MB][0]);                                   \
    const uint32 _eys[4] = {EY.x, EY.y, EY.z, EY.w};                                 \
    const uint32 _ezs[4] = {EZ.x, EZ.y, EZ.z, EZ.w};                                 \
    const uint32 _ms[4] = {_m.x, _m.y, _m.z, _m.w};                                  \
    uint32 _o[4];                                                                    \
    _Pragma("unroll") for (int _p = 0; _p < 4; ++_p) {                               \
      const f16x2 _a = __builtin_bit_cast(f16x2, _eys[_p]) * rx2;                    \
      const f16x2 _b2 = __builtin_bit_cast(f16x2, _ezs[_p]) * ry2;                   \
      const f16x2 _mx = __builtin_elementwise_max(_a, _b2);                          \
      _o[_p] = __builtin_bit_cast(uint32, _mx) & _ms[_p];                            \
    }                                                                                \
    uint4 _st; _st.x = _o[0]; _st.y = _o[1]; _st.z = _o[2]; _st.w = _o[3];           \
    *(uint4*)(DST) = _st;                                                            \
  } while (0)

#define DO_MFMA(BUF, Bq00, Bq01, Bq10, Bq11)                                        \
  do {                                                                              \
    const char* _Pb = (const char*)&P[BUF][0];                                      \
    const f16x8 a00 = *(const f16x8*)(_Pb + ar0 + ((((unsigned)(kgrp * 16))) ^ asw));        \
    const f16x8 a01 = *(const f16x8*)(_Pb + ar0 + (((unsigned)(64 + kgrp * 16)) ^ asw));     \
    const f16x8 a10 = *(const f16x8*)(_Pb + ar1 + ((((unsigned)(kgrp * 16))) ^ asw));        \
    const f16x8 a11 = *(const f16x8*)(_Pb + ar1 + (((unsigned)(64 + kgrp * 16)) ^ asw));     \
    __builtin_amdgcn_s_setprio(1);                                                  \
    acc00 = __builtin_amdgcn_mfma_f32_16x16x32_f16(a00, Bq00, acc00, 0, 0, 0);      \
    acc01 = __builtin_amdgcn_mfma_f32_16x16x32_f16(a00, Bq01, acc01, 0, 0, 0);      \
    acc10 = __builtin_amdgcn_mfma_f32_16x16x32_f16(a10, Bq00, acc10, 0, 0, 0);      \
    acc11 = __builtin_amdgcn_mfma_f32_16x16x32_f16(a10, Bq01, acc11, 0, 0, 0);      \
    acc00 = __builtin_amdgcn_mfma_f32_16x16x32_f16(a01, Bq10, acc00, 0, 0, 0);      \
    acc01 = __builtin_amdgcn_mfma_f32_16x16x32_f16(a01, Bq11, acc01, 0, 0, 0);      \
    acc10 = __builtin_amdgcn_mfma_f32_16x16x32_f16(a11, Bq10, acc10, 0, 0, 0);      \
    acc11 = __builtin_amdgcn_mfma_f32_16x16x32_f16(a11, Bq11, acc11, 0, 0, 0);      \
    __builtin_amdgcn_s_setprio(0);                                                  \
  } while (0)

#pragma unroll 1
  for (int rep = 0; rep < K4_REPS; ++rep) {
    acc00 = (f32x4){0.f, 0.f, 0.f, 0.f};
    acc01 = (f32x4){0.f, 0.f, 0.f, 0.f};
    acc10 = (f32x4){0.f, 0.f, 0.f, 0.f};
    acc11 = (f32x4){0.f, 0.f, 0.f, 0.f};

    LOADALL(0, mb0, ey0, ez0, B000, B001, B010, B011);
    LOADALL(1, mb1, ey1, ez1, B100, B101, B110, B111);
    __syncthreads();
    PGEN(pdst0, mb0, ey0, ez0);
    BARRIER_LDS();

    for (int s = 0; s < 32; s += 2) {
      PGEN(pdst1, mb1, ey1, ez1);
      DO_MFMA(0, B000, B001, B010, B011);
      if (s + 2 < 32) LOADALL(s + 2, mb0, ey0, ez0, B000, B001, B010, B011);
      BARRIER_LDS();
      DO_MFMA(1, B100, B101, B110, B111);
      if (s + 2 < 32) PGEN(pdst0, mb0, ey0, ez0);
      if (s + 3 < 32) LOADALL(s + 3, mb1, ey1, ez1, B100, B101, B110, B111);
      BARRIER_LDS();
    }
    asm volatile("" ::
                     "v"(acc00[0]), "v"(acc00[1]), "v"(acc00[2]), "v"(acc00[3]),
                     "v"(acc01[0]), "v"(acc01[1]), "v"(acc01[2]), "v"(acc01[3]),
                     "v"(acc10[0]), "v"(acc10[1]), "v"(acc10[2]), "v"(acc10[3]),
                     "v"(acc11[0]), "v"(acc11[1]), "v"(acc11[2]), "v"(acc11[3]));
  }

#undef LOADALL
#undef PGEN
#undef DO_MFMA

  const int orow = rowbase + kgrp * 4;
  const int ocol = wc * 32 + l15;
  float* aP = part + (size_t)kq * NN * FO + (size_t)orow * FO + ocol;
#pragma unroll
  for (int r = 0; r < 4; ++r) {
    aP[(size_t)r * FO] = acc00[r];
    aP[(size_t)r * FO + 16] = acc01[r];
    aP[(size_t)(16 + r) * FO] = acc10[r];
    aP[(size_t)(16 + r) * FO + 16] = acc11[r];
  }
}

// ---------------------------------------------------------------------------
// K5, rep-looped.
// ---------------------------------------------------------------------------
__global__ __launch_bounds__(256) void k5_fin(const float* __restrict__ part,
                                              const float* __restrict__ corr,
                                              float* __restrict__ out) {
  const int idx = blockIdx.x * 256 + threadIdx.x;
#pragma unroll 1
  for (int rep = 0; rep < K5_REPS; ++rep) {
    asm volatile("" ::: "memory");
    const float4 p0 = ((const float4*)part)[idx];
    const float4 p1 = ((const float4*)(part + (size_t)NN * FO))[idx];
    const float4 p2 = ((const float4*)(part + (size_t)2 * NN * FO))[idx];
    const float4 p3 = ((const float4*)(part + (size_t)3 * NN * FO))[idx];
    const float4 c = ((const float4*)corr)[idx & 31];
    float4 v;
    v.x = p0.x + p1.x + p2.x + p3.x + c.x;
    v.y = p0.y + p1.y + p2.y + p3.y + c.y;
    v.z = p0.z + p1.z + p2.z + p3.z + c.z;
    v.w = p0.w + p1.w + p2.w + p3.w + c.w;
    v.x = (v.x > 0.f) ? v.x : (expf(v.x) - 1.f);
    v.y = (v.y > 0.f) ? v.y : (expf(v.y) - 1.f);
    v.z = (v.z > 0.f) ? v.z : (expf(v.z) - 1.f);
    v.w = (v.w > 0.f) ? v.w : (expf(v.w) - 1.f);
    ((float4*)out)[idx] = v;
  }
}

// ---------------------------------------------------------------------------
extern "C" void kernel_launch(void* const* d_in, const int* in_sizes, int n_in,
                              void* d_out, int out_size, void* d_ws, size_t ws_size,
                              hipStream_t stream) {
  const float* h = (const float*)d_in[0];
  const int* adj = (const int*)d_in[1];
  const float* W = (const float*)d_in[2];
  const float* b = (const float*)d_in[3];
  const float* a = (const float*)d_in[4];
  float* out = (float*)d_out;
  char* ws = (char*)d_ws;

  float* Wh = (float*)(ws + 0);                                   // 4 MB  [k1..k3]
  _Float16* Wfrag = (_Float16*)(ws + 0x400000);                   // 2 MB  [k3..k4]
  uchar* bits = (uchar*)(ws + 0x600000);                          // 8 MB  [k2..k4]
  float2* zpart = (float2*)(ws + 0xE00000);                       // 8 MB  [k2..k3]
  float4* r4 = (float4*)(ws + 0x1600000);                         // 128 KB
  float4* c4 = (float4*)(ws + 0x1620000);                         // 128 KB
  float2* r2 = (float2*)(ws + 0x1640000);                         // 64 KB
  _Float16* ey16 = (_Float16*)(ws + 0x1650000);                   // 16 KB
  _Float16* ez16 = (_Float16*)(ws + 0x1654000);                   // 16 KB
  float* s2x = (float*)(ws + 0x1658000);                          // 32 KB
  float* corr = (float*)(ws + 0x1660000);                         // 512 B
  float* part = (float*)(ws + 0x1700000);                         // 16 MB [k4..k5]

  k1_wh<<<NN / 32, 256, 0, stream>>>(h, W, b, a, Wh, r4, c4, r2, ey16, ez16, s2x, corr);
  k2_stats<<<512, 256, 0, stream>>>(adj, r4, s2x, bits, zpart);
  k3_scale<<<NN / 64, 256, 0, stream>>>(Wh, c4, zpart, Wfrag, corr);
  k4_main<<<1024, 256, 0, stream>>>(bits, r2, ey16, ez16, Wfrag, part);
  k5_fin<<<(NN * FO / 4) / 256, 256, 0, stream>>>(part, corr, out);
}

// Round 15
// 119.407 us; speedup vs baseline: 10.8098x; 10.8098x over previous
//
#include <hip/hip_runtime.h>

#define NN 8192
#define FI 256
#define FO 128
#define GAT_ALPHA 0.2f

typedef _Float16 f16x8 __attribute__((ext_vector_type(8)));
typedef _Float16 f16x2 __attribute__((ext_vector_type(2)));
typedef float f32x4 __attribute__((ext_vector_type(4)));
typedef unsigned char uchar;
typedef unsigned int uint32;

// ---------------------------------------------------------------------------
// K1 v2: Wh = h@W^T + b (fp32) + fused score/exp-table tail.
// Conflict-free LDS: hs as float4[16][65] (b128 writes, broadcast b128 reads);
// wt as float[32][132] (stride=4 mod 32: transpose-writes 2-way=free, b128
// reads at throughput floor). 16 rows/block, grid 512 = 2 blocks/CU.
// ---------------------------------------------------------------------------
__global__ __launch_bounds__(256) void k1_wh(const float* __restrict__ h,
                                             const float* __restrict__ W,
                                             const float* __restrict__ bias,
                                             const float* __restrict__ a,
                                             float* __restrict__ Wh,
                                             float4* __restrict__ r4,
                                             float4* __restrict__ c4,
                                             float2* __restrict__ r2,
                                             _Float16* __restrict__ ey16,
                                             _Float16* __restrict__ ez16,
                                             float* __restrict__ s2x,
                                             float* __restrict__ corr) {
  __shared__ __align__(16) float4 hs4[16][65];   // 16 rows x 64 quads (+1 pad)
  __shared__ float wt[32][132];                  // [k][f], stride 132 (=4 mod 32)
  const int t = threadIdx.x;
  const int j0 = blockIdx.x * 16;
  if (blockIdx.x == 0 && t < FO) corr[t] = 0.f;
  // load h tile: linear lane->quad map; coalesced global, floor-only LDS writes
#pragma unroll
  for (int e = 0; e < 4; ++e) {
    const int i = t + 256 * e;
    const int row = i >> 6, q = i & 63;
    hs4[row][q] = *(const float4*)(h + (size_t)(j0 + row) * FI + 4 * q);
  }
  const int f4 = (t & 31) * 4;
  const int r0 = (t >> 5) * 2;
  float acc[2][4];
#pragma unroll
  for (int r = 0; r < 2; ++r)
#pragma unroll
    for (int e = 0; e < 4; ++e) acc[r][e] = 0.f;

  for (int kc = 0; kc < FI; kc += 32) {
    __syncthreads();
    {
      const int f = t >> 1, kb = (t & 1) * 16;
      const float* wsrc = W + (size_t)f * FI + kc + kb;
#pragma unroll
      for (int e = 0; e < 4; ++e) {
        const float4 wv = *(const float4*)(wsrc + 4 * e);
        wt[kb + 4 * e + 0][f] = wv.x;
        wt[kb + 4 * e + 1][f] = wv.y;
        wt[kb + 4 * e + 2][f] = wv.z;
        wt[kb + 4 * e + 3][f] = wv.w;
      }
    }
    __syncthreads();
#pragma unroll
    for (int kk = 0; kk < 8; ++kk) {
      float4 wv[4];
#pragma unroll
      for (int i = 0; i < 4; ++i) wv[i] = *(const float4*)&wt[4 * kk + i][f4];
      float4 hv[2];
#pragma unroll
      for (int r = 0; r < 2; ++r) hv[r] = hs4[r0 + r][(kc >> 2) + kk];
#pragma unroll
      for (int r = 0; r < 2; ++r) {
        acc[r][0] += hv[r].x * wv[0].x + hv[r].y * wv[1].x + hv[r].z * wv[2].x + hv[r].w * wv[3].x;
        acc[r][1] += hv[r].x * wv[0].y + hv[r].y * wv[1].y + hv[r].z * wv[2].y + hv[r].w * wv[3].y;
        acc[r][2] += hv[r].x * wv[0].z + hv[r].y * wv[1].z + hv[r].z * wv[2].z + hv[r].w * wv[3].z;
        acc[r][3] += hv[r].x * wv[0].w + hv[r].y * wv[1].w + hv[r].z * wv[2].w + hv[r].w * wv[3].w;
      }
    }
  }
  const float4 bv = *(const float4*)&bias[f4];
  const float4 a1v = *(const float4*)&a[f4];
  const float4 a2v = *(const float4*)&a[FO + f4];
  float s1p[2], s2p[2];
#pragma unroll
  for (int r = 0; r < 2; ++r) {
    float4 o;
    o.x = acc[r][0] + bv.x;
    o.y = acc[r][1] + bv.y;
    o.z = acc[r][2] + bv.z;
    o.w = acc[r][3] + bv.w;
    *(float4*)&Wh[(size_t)(j0 + r0 + r) * FO + f4] = o;
    s1p[r] = o.x * a1v.x + o.y * a1v.y + o.z * a1v.z + o.w * a1v.w;
    s2p[r] = o.x * a2v.x + o.y * a2v.y + o.z * a2v.z + o.w * a2v.w;
  }
#pragma unroll
  for (int m = 16; m >= 1; m >>= 1) {
#pragma unroll
    for (int r = 0; r < 2; ++r) {
      s1p[r] += __shfl_xor(s1p[r], m);
      s2p[r] += __shfl_xor(s2p[r], m);
    }
  }
  if ((t & 31) == 0) {
#pragma unroll
    for (int r = 0; r < 2; ++r) {
      const int j = j0 + r0 + r;
      const float s1 = s1p[r], s2 = s2p[r];
      const float e1 = expf(s1), e1a = expf(GAT_ALPHA * s1);
      const float e2 = expf(s2), e2a = expf(GAT_ALPHA * s2);
      float4 rv; rv.x = s1; rv.y = e1; rv.z = e1a; rv.w = 0.f;
      float4 cv; cv.x = s2; cv.y = e2; cv.z = e2a; cv.w = 0.f;
      r4[j] = rv;
      c4[j] = cv;
      r2[j] = make_float2(e1, e1a);
      ey16[j] = (_Float16)e2;
      ez16[j] = (_Float16)e2a;
      s2x[j] = s2;
    }
  }
}

// ---------------------------------------------------------------------------
// K2: single pass over adj (268 MB HBM floor). Thread owns 8 consecutive j
// (2x int4 = 32 B/lane), packs 8 activity bits into one byte, coalesced
// byte stores; 8 accP/accN register accumulators.
// ---------------------------------------------------------------------------
__global__ __launch_bounds__(256) void k2_stats(const int* __restrict__ adj,
                                                const float4* __restrict__ r4,
                                                const float* __restrict__ s2x,
                                                uchar* __restrict__ bitsB,
                                                float2* __restrict__ zpart) {
  __shared__ float4 rs[64];
  const int t = threadIdx.x;
  const int jc = blockIdx.x & 3;
  const int ic = blockIdx.x >> 2;
  const int i0 = ic * 64;
  const int j0 = jc * 2048 + t * 8;
  if (t < 64) rs[t] = r4[i0 + t];
  const float4 ca = *(const float4*)(s2x + j0);
  const float4 cb = *(const float4*)(s2x + j0 + 4);
  const float cx[8] = {ca.x, ca.y, ca.z, ca.w, cb.x, cb.y, cb.z, cb.w};
  float accP[8], accN[8];
#pragma unroll
  for (int e = 0; e < 8; ++e) { accP[e] = 0.f; accN[e] = 0.f; }
  __syncthreads();
  const int4* ap = (const int4*)(adj + (size_t)i0 * NN + j0);
  uchar* bp = bitsB + (size_t)i0 * (NN / 8) + jc * 256 + t;
  for (int ir = 0; ir < 64; ir += 8) {
    int4 av[8][2];
#pragma unroll
    for (int u = 0; u < 8; ++u) {
      av[u][0] = ap[(size_t)(ir + u) * (NN / 4)];
      av[u][1] = ap[(size_t)(ir + u) * (NN / 4) + 1];
    }
#pragma unroll
    for (int u = 0; u < 8; ++u) {
      const float4 ri = rs[ir + u];
      const int aa[8] = {av[u][0].x, av[u][0].y, av[u][0].z, av[u][0].w,
                         av[u][1].x, av[u][1].y, av[u][1].z, av[u][1].w};
      uint32 byte = 0;
#pragma unroll
      for (int e = 0; e < 8; ++e) {
        const bool act = aa[e] > 0;
        byte |= act ? (1u << e) : 0u;
        const bool pos = (ri.x + cx[e]) >= 0.f;
        accP[e] += (act && pos) ? ri.y : 0.f;
        accN[e] += (act && !pos) ? ri.z : 0.f;
      }
      bp[(size_t)(ir + u) * (NN / 8)] = (uchar)byte;
    }
  }
  float2* zp = zpart + (size_t)ic * NN + j0;
#pragma unroll
  for (int e = 0; e < 8; ++e) zp[e] = make_float2(accP[e], accN[e]);
}

// ---------------------------------------------------------------------------
// K3: Z_j from 128 partials; emit Wfrag in MFMA-B-fragment-major layout.
// Empty cols -> corr[f] (uniform softmax fix).
// ---------------------------------------------------------------------------
__global__ __launch_bounds__(256) void k3_scale(const float* __restrict__ Wh,
                                                const float4* __restrict__ c4,
                                                const float2* __restrict__ zpart,
                                                _Float16* __restrict__ Wfrag,
                                                float* __restrict__ corr) {
  __shared__ float rz[64];
  __shared__ int emp[64];
  __shared__ float2 psum[256];
  __shared__ __align__(16) _Float16 tile[FO * 64];
  const int t = threadIdx.x;
  const int j0 = blockIdx.x * 64;
  {
    const int jl = t & 63, q = t >> 6;
    float p = 0.f, n = 0.f;
    for (int ic = q * 32; ic < q * 32 + 32; ++ic) {
      const float2 z = zpart[(size_t)ic * NN + j0 + jl];
      p += z.x;
      n += z.y;
    }
    psum[t] = make_float2(p, n);
  }
  __syncthreads();
  if (t < 64) {
    const float p = psum[t].x + psum[64 + t].x + psum[128 + t].x + psum[192 + t].x;
    const float n = psum[t].y + psum[64 + t].y + psum[128 + t].y + psum[192 + t].y;
    const float4 cj = c4[j0 + t];
    const float Z = cj.y * p + cj.z * n;
    rz[t] = (Z > 0.f) ? 1.f / Z : 0.f;
    emp[t] = (Z > 0.f) ? 0 : 1;
  }
  __syncthreads();
  const int f = t & 127, half = t >> 7;
  const unsigned swf = (unsigned)((f & 7) << 4);
  for (int r = half; r < 64; r += 2) {
    const float v = Wh[(size_t)(j0 + r) * FO + f];
    *(_Float16*)((char*)tile + f * 128 + (((unsigned)(r * 2)) ^ swf)) =
        (_Float16)(v * rz[r]);
    if (emp[r]) atomicAdd(&corr[f], v * (1.f / 8192.f));
  }
  __syncthreads();
#pragma unroll
  for (int q = 0; q < 4; ++q) {
    const int G = t + 256 * q;
    const int kcfb = G >> 6, gl = G & 63;
    const int kc = kcfb >> 3, fb = kcfb & 7;
    const int gf = fb * 16 + (gl & 15);
    const int jloc = kc * 32 + (gl >> 4) * 8;
    const f16x8 v = *(const f16x8*)((const char*)tile + gf * 128 +
                                    (((unsigned)(jloc * 2)) ^ ((unsigned)((gf & 7) << 4))));
    ((f16x8*)Wfrag)[(size_t)(((j0 >> 5) + kc) * 8 + fb) * 64 + gl] = v;
  }
}

// ---------------------------------------------------------------------------
// K4 (R11 champion): partial h' = P~ @ (Wh/Z) -> part[kq].
// BM=32, 256 thr = 4 waves (1x4), ksplit=4 (2048 cols, 32 steps of 64).
// ---------------------------------------------------------------------------
#define BARRIER_LDS()                                          \
  do {                                                         \
    __builtin_amdgcn_sched_barrier(0);                         \
    asm volatile("s_waitcnt lgkmcnt(0)" ::: "memory");         \
    __builtin_amdgcn_s_barrier();                              \
    __builtin_amdgcn_sched_barrier(0);                         \
  } while (0)

__global__ __launch_bounds__(256) void k4_main(const uchar* __restrict__ bitsB,
                                               const float2* __restrict__ r2,
                                               const _Float16* __restrict__ ey16,
                                               const _Float16* __restrict__ ez16,
                                               const _Float16* __restrict__ Wfrag,
                                               float* __restrict__ part) {
  __shared__ __align__(16) _Float16 P[2][32 * 64];
  __shared__ uint32 lut[256][4];
  const int t = threadIdx.x;
  const int rowtile = blockIdx.x >> 2;
  const int kq = blockIdx.x & 3;
  const int rowbase = rowtile * 32;
  const int koff = kq * 2048;

  {
#pragma unroll
    for (int p = 0; p < 4; ++p) {
      const uint32 lo = ((t >> (2 * p)) & 1) ? 0x0000FFFFu : 0u;
      const uint32 hi = ((t >> (2 * p + 1)) & 1) ? 0xFFFF0000u : 0u;
      lut[t][p] = lo | hi;
    }
  }

  const int pr = t >> 3, jq = t & 7;
  const float2 rr = r2[rowbase + pr];
  const f16x2 rx2 = {(_Float16)rr.x, (_Float16)rr.x};
  const f16x2 ry2 = {(_Float16)rr.y, (_Float16)rr.y};
  const uchar* bp = bitsB + (size_t)(rowbase + pr) * (NN / 8) + (koff >> 3) + jq;
  const _Float16* eyp = ey16 + koff + jq * 8;
  const _Float16* ezp = ez16 + koff + jq * 8;
  char* const pdst0 = (char*)&P[0][0] + pr * 128 + (((unsigned)(jq * 16)) ^ ((unsigned)((pr & 7) << 4)));
  char* const pdst1 = (char*)&P[1][0] + pr * 128 + (((unsigned)(jq * 16)) ^ ((unsigned)((pr & 7) << 4)));

  const int lane = t & 63, wc = t >> 6;
  const int kgrp = lane >> 4, l15 = lane & 15;
  const unsigned asw = (unsigned)((l15 & 7) << 4);
  const int ar0 = l15 * 128;
  const int ar1 = ar0 + 16 * 128;

  f32x4 acc00 = {0.f, 0.f, 0.f, 0.f}, acc01 = {0.f, 0.f, 0.f, 0.f};
  f32x4 acc10 = {0.f, 0.f, 0.f, 0.f}, acc11 = {0.f, 0.f, 0.f, 0.f};

  uchar mb0, mb1;
  uint4 ey0, ez0, ey1, ez1;
  f16x8 B000, B001, B010, B011, B100, B101, B110, B111;

#define LOADALL(S, MB, EY, EZ, Bq00, Bq01, Bq10, Bq11)                              \
  do {                                                                              \
    MB = bp[(S) * 8];                                                               \
    EY = *(const uint4*)(eyp + (S) * 64);                                           \
    EZ = *(const uint4*)(ezp + (S) * 64);                                           \
    const _Float16* _b = Wfrag + ((size_t)((kq * 64 + (S) * 2) * 8 + wc * 2) * 64 + lane) * 8; \
    Bq00 = *(const f16x8*)(_b);                                                     \
    Bq01 = *(const f16x8*)(_b + 512);                                               \
    Bq10 = *(const f16x8*)(_b + 4096);                                              \
    Bq11 = *(const f16x8*)(_b + 4096 + 512);                                        \
  } while (0)

#define PGEN(DST, MB, EY, EZ)                                                        \
  do {                                                                               \
    const uint4 _m = *(const uint4*)(&lut[MB][0]);                                   \
    const uint32 _eys[4] = {EY.x, EY.y, EY.z, EY.w};                                 \
    const uint32 _ezs[4] = {EZ.x, EZ.y, EZ.z, EZ.w};                                 \
    const uint32 _ms[4] = {_m.x, _m.y, _m.z, _m.w};                                  \
    uint32 _o[4];                                                                    \
    _Pragma("unroll") for (int _p = 0; _p < 4; ++_p) {                               \
      const f16x2 _a = __builtin_bit_cast(f16x2, _eys[_p]) * rx2;                    \
      const f16x2 _b2 = __builtin_bit_cast(f16x2, _ezs[_p]) * ry2;                   \
      const f16x2 _mx = __builtin_elementwise_max(_a, _b2);                          \
      _o[_p] = __builtin_bit_cast(uint32, _mx) & _ms[_p];                            \
    }                                                                                \
    uint4 _st; _st.x = _o[0]; _st.y = _o[1]; _st.z = _o[2]; _st.w = _o[3];           \
    *(uint4*)(DST) = _st;                                                            \
  } while (0)

#define DO_MFMA(BUF, Bq00, Bq01, Bq10, Bq11)                                        \
  do {                                                                              \
    const char* _Pb = (const char*)&P[BUF][0];                                      \
    const f16x8 a00 = *(const f16x8*)(_Pb + ar0 + ((((unsigned)(kgrp * 16))) ^ asw));        \
    const f16x8 a01 = *(const f16x8*)(_Pb + ar0 + (((unsigned)(64 + kgrp * 16)) ^ asw));     \
    const f16x8 a10 = *(const f16x8*)(_Pb + ar1 + ((((unsigned)(kgrp * 16))) ^ asw));        \
    const f16x8 a11 = *(const f16x8*)(_Pb + ar1 + (((unsigned)(64 + kgrp * 16)) ^ asw));     \
    __builtin_amdgcn_s_setprio(1);                                                  \
    acc00 = __builtin_amdgcn_mfma_f32_16x16x32_f16(a00, Bq00, acc00, 0, 0, 0);      \
    acc01 = __builtin_amdgcn_mfma_f32_16x16x32_f16(a00, Bq01, acc01, 0, 0, 0);      \
    acc10 = __builtin_amdgcn_mfma_f32_16x16x32_f16(a10, Bq00, acc10, 0, 0, 0);      \
    acc11 = __builtin_amdgcn_mfma_f32_16x16x32_f16(a10, Bq01, acc11, 0, 0, 0);      \
    acc00 = __builtin_amdgcn_mfma_f32_16x16x32_f16(a01, Bq10, acc00, 0, 0, 0);      \
    acc01 = __builtin_amdgcn_mfma_f32_16x16x32_f16(a01, Bq11, acc01, 0, 0, 0);      \
    acc10 = __builtin_amdgcn_mfma_f32_16x16x32_f16(a11, Bq10, acc10, 0, 0, 0);      \
    acc11 = __builtin_amdgcn_mfma_f32_16x16x32_f16(a11, Bq11, acc11, 0, 0, 0);      \
    __builtin_amdgcn_s_setprio(0);                                                  \
  } while (0)

  // ---- prologue (sync covers lut writes before first PGEN lut read)
  LOADALL(0, mb0, ey0, ez0, B000, B001, B010, B011);
  LOADALL(1, mb1, ey1, ez1, B100, B101, B110, B111);
  __syncthreads();
  PGEN(pdst0, mb0, ey0, ez0);
  BARRIER_LDS();

  for (int s = 0; s < 32; s += 2) {
    PGEN(pdst1, mb1, ey1, ez1);                       // P for step s+1
    DO_MFMA(0, B000, B001, B010, B011);               // step s
    if (s + 2 < 32) LOADALL(s + 2, mb0, ey0, ez0, B000, B001, B010, B011);
    BARRIER_LDS();
    DO_MFMA(1, B100, B101, B110, B111);               // step s+1
    if (s + 2 < 32) PGEN(pdst0, mb0, ey0, ez0);       // P for step s+2
    if (s + 3 < 32) LOADALL(s + 3, mb1, ey1, ez1, B100, B101, B110, B111);
    BARRIER_LDS();
  }

#undef LOADALL
#undef PGEN
#undef DO_MFMA

  const int orow = rowbase + kgrp * 4;
  const int ocol = wc * 32 + l15;
  float* aP = part + (size_t)kq * NN * FO + (size_t)orow * FO + ocol;
#pragma unroll
  for (int r = 0; r < 4; ++r) {
    aP[(size_t)r * FO] = acc00[r];
    aP[(size_t)r * FO + 16] = acc01[r];
    aP[(size_t)(16 + r) * FO] = acc10[r];
    aP[(size_t)(16 + r) * FO + 16] = acc11[r];
  }
}

// ---------------------------------------------------------------------------
// K5: out = elu(sum_q part[q] + corr), 4 partials
// ---------------------------------------------------------------------------
__global__ __launch_bounds__(256) void k5_fin(const float* __restrict__ part,
                                              const float* __restrict__ corr,
                                              float* __restrict__ out) {
  const int idx = blockIdx.x * 256 + threadIdx.x;
  const float4 p0 = ((const float4*)part)[idx];
  const float4 p1 = ((const float4*)(part + (size_t)NN * FO))[idx];
  const float4 p2 = ((const float4*)(part + (size_t)2 * NN * FO))[idx];
  const float4 p3 = ((const float4*)(part + (size_t)3 * NN * FO))[idx];
  const float4 c = ((const float4*)corr)[idx & 31];
  float4 v;
  v.x = p0.x + p1.x + p2.x + p3.x + c.x;
  v.y = p0.y + p1.y + p2.y + p3.y + c.y;
  v.z = p0.z + p1.z + p2.z + p3.z + c.z;
  v.w = p0.w + p1.w + p2.w + p3.w + c.w;
  v.x = (v.x > 0.f) ? v.x : (expf(v.x) - 1.f);
  v.y = (v.y > 0.f) ? v.y : (expf(v.y) - 1.f);
  v.z = (v.z > 0.f) ? v.z : (expf(v.z) - 1.f);
  v.w = (v.w > 0.f) ? v.w : (expf(v.w) - 1.f);
  ((float4*)out)[idx] = v;
}

// ---------------------------------------------------------------------------
extern "C" void kernel_launch(void* const* d_in, const int* in_sizes, int n_in,
                              void* d_out, int out_size, void* d_ws, size_t ws_size,
                              hipStream_t stream) {
  const float* h = (const float*)d_in[0];
  const int* adj = (const int*)d_in[1];
  const float* W = (const float*)d_in[2];
  const float* b = (const float*)d_in[3];
  const float* a = (const float*)d_in[4];
  float* out = (float*)d_out;
  char* ws = (char*)d_ws;

  float* Wh = (float*)(ws + 0);                                   // 4 MB  [k1..k3]
  _Float16* Wfrag = (_Float16*)(ws + 0x400000);                   // 2 MB  [k3..k4]
  uchar* bits = (uchar*)(ws + 0x600000);                          // 8 MB  [k2..k4]
  float2* zpart = (float2*)(ws + 0xE00000);                       // 8 MB  [k2..k3]
  float4* r4 = (float4*)(ws + 0x1600000);                         // 128 KB
  float4* c4 = (float4*)(ws + 0x1620000);                         // 128 KB
  float2* r2 = (float2*)(ws + 0x1640000);                         // 64 KB
  _Float16* ey16 = (_Float16*)(ws + 0x1650000);                   // 16 KB
  _Float16* ez16 = (_Float16*)(ws + 0x1654000);                   // 16 KB
  float* s2x = (float*)(ws + 0x1658000);                          // 32 KB
  float* corr = (float*)(ws + 0x1660000);                         // 512 B
  float* part = (float*)(ws + 0x1700000);                         // 16 MB [k4..k5]

  k1_wh<<<NN / 16, 256, 0, stream>>>(h, W, b, a, Wh, r4, c4, r2, ey16, ez16, s2x, corr);
  k2_stats<<<512, 256, 0, stream>>>(adj, r4, s2x, bits, zpart);
  k3_scale<<<NN / 64, 256, 0, stream>>>(Wh, c4, zpart, Wfrag, corr);
  k4_main<<<1024, 256, 0, stream>>>(bits, r2, ey16, ez16, Wfrag, part);
  k5_fin<<<(NN * FO / 4) / 256, 256, 0, stream>>>(part, corr, out);
}

// Round 16
// 117.243 us; speedup vs baseline: 11.0093x; 1.0185x over previous
//
#include <hip/hip_runtime.h>

#define NN 8192
#define FI 256
#define FO 128
#define GAT_ALPHA 0.2f

typedef _Float16 f16x8 __attribute__((ext_vector_type(8)));
typedef _Float16 f16x2 __attribute__((ext_vector_type(2)));
typedef float f32x4 __attribute__((ext_vector_type(4)));
typedef unsigned char uchar;
typedef unsigned int uint32;

// ---------------------------------------------------------------------------
// K1s: scores WITHOUT the GEMM.  s1 = h@(W^T a1) + b.a1 ; s2 likewise.
// Per block: cooperative wa1/wa2 (W is L2-hot, 128KB), then 32 rows of
// lane-dot + 64-lane shfl reduce. Writes all score/exp tables.
// ---------------------------------------------------------------------------
__global__ __launch_bounds__(256) void k1s_scores(const float* __restrict__ h,
                                                  const float* __restrict__ W,
                                                  const float* __restrict__ bias,
                                                  const float* __restrict__ a,
                                                  float4* __restrict__ r4,
                                                  float4* __restrict__ c4,
                                                  float2* __restrict__ r2,
                                                  _Float16* __restrict__ ey16,
                                                  _Float16* __restrict__ ez16,
                                                  float* __restrict__ s2x,
                                                  float* __restrict__ corr) {
  __shared__ __align__(16) float wa1[FI];
  __shared__ __align__(16) float wa2[FI];
  __shared__ float cb[2];
  const int t = threadIdx.x;
  const int j0 = blockIdx.x * 32;
  if (blockIdx.x == 0 && t < FO) corr[t] = 0.f;
  {
    float sa = 0.f, sb = 0.f;
    for (int f = 0; f < FO; ++f) {
      const float w = W[(size_t)f * FI + t];
      sa += a[f] * w;
      sb += a[FO + f] * w;
    }
    wa1[t] = sa;
    wa2[t] = sb;
  }
  if (t < 64) {
    float c1 = bias[t] * a[t] + bias[t + 64] * a[t + 64];
    float c2 = bias[t] * a[FO + t] + bias[t + 64] * a[FO + t + 64];
#pragma unroll
    for (int o = 32; o >= 1; o >>= 1) {
      c1 += __shfl_xor(c1, o);
      c2 += __shfl_xor(c2, o);
    }
    if (t == 0) { cb[0] = c1; cb[1] = c2; }
  }
  __syncthreads();
  const int lane = t & 63, wv = t >> 6;
  const float4 w1v = *(const float4*)&wa1[lane * 4];
  const float4 w2v = *(const float4*)&wa2[lane * 4];
  const float cb1 = cb[0], cb2 = cb[1];
#pragma unroll
  for (int rr = 0; rr < 8; ++rr) {
    const int j = j0 + wv * 8 + rr;
    const float4 hv = *(const float4*)&h[(size_t)j * FI + lane * 4];
    float s1 = hv.x * w1v.x + hv.y * w1v.y + hv.z * w1v.z + hv.w * w1v.w;
    float s2 = hv.x * w2v.x + hv.y * w2v.y + hv.z * w2v.z + hv.w * w2v.w;
#pragma unroll
    for (int o = 32; o >= 1; o >>= 1) {
      s1 += __shfl_xor(s1, o);
      s2 += __shfl_xor(s2, o);
    }
    if (lane == 0) {
      s1 += cb1;
      s2 += cb2;
      const float e1 = expf(s1), e1a = expf(GAT_ALPHA * s1);
      const float e2 = expf(s2), e2a = expf(GAT_ALPHA * s2);
      float4 rv; rv.x = s1; rv.y = e1; rv.z = e1a; rv.w = 0.f;
      float4 cv; cv.x = s2; cv.y = e2; cv.z = e2a; cv.w = 0.f;
      r4[j] = rv;
      c4[j] = cv;
      r2[j] = make_float2(e1, e1a);
      ey16[j] = (_Float16)e2;
      ez16[j] = (_Float16)e2a;
      s2x[j] = s2;
    }
  }
}

// ---------------------------------------------------------------------------
// MEGA: two block types in one dispatch (overlap compute under HBM wall).
//  blocks 0..511   : adj scan (R15 k2 body) -> bits, zpart
//  blocks 512..1023: Wh GEMM  (R15 k1 body) -> Wh
// LDS unioned: scan uses 1KB of the 33.5KB the GEMM needs. 4 blocks/CU.
// ---------------------------------------------------------------------------
__global__ __launch_bounds__(256) void mega(const int* __restrict__ adj,
                                            const float* __restrict__ h,
                                            const float* __restrict__ W,
                                            const float* __restrict__ bias,
                                            const float4* __restrict__ r4,
                                            const float* __restrict__ s2x,
                                            uchar* __restrict__ bitsB,
                                            float2* __restrict__ zpart,
                                            float* __restrict__ Wh) {
  __shared__ __align__(16) char smem[33536];
  const int t = threadIdx.x;
  if (blockIdx.x < 512) {
    // ---------------- scan path (R15 k2, verbatim) ----------------
    float4* rs = (float4*)smem;
    const int jc = blockIdx.x & 3;
    const int ic = blockIdx.x >> 2;
    const int i0 = ic * 64;
    const int j0 = jc * 2048 + t * 8;
    if (t < 64) rs[t] = r4[i0 + t];
    const float4 ca = *(const float4*)(s2x + j0);
    const float4 cbv = *(const float4*)(s2x + j0 + 4);
    const float cx[8] = {ca.x, ca.y, ca.z, ca.w, cbv.x, cbv.y, cbv.z, cbv.w};
    float accP[8], accN[8];
#pragma unroll
    for (int e = 0; e < 8; ++e) { accP[e] = 0.f; accN[e] = 0.f; }
    __syncthreads();
    const int4* ap = (const int4*)(adj + (size_t)i0 * NN + j0);
    uchar* bp = bitsB + (size_t)i0 * (NN / 8) + jc * 256 + t;
    for (int ir = 0; ir < 64; ir += 8) {
      int4 av[8][2];
#pragma unroll
      for (int u = 0; u < 8; ++u) {
        av[u][0] = ap[(size_t)(ir + u) * (NN / 4)];
        av[u][1] = ap[(size_t)(ir + u) * (NN / 4) + 1];
      }
#pragma unroll
      for (int u = 0; u < 8; ++u) {
        const float4 ri = rs[ir + u];
        const int aa[8] = {av[u][0].x, av[u][0].y, av[u][0].z, av[u][0].w,
                           av[u][1].x, av[u][1].y, av[u][1].z, av[u][1].w};
        uint32 byte = 0;
#pragma unroll
        for (int e = 0; e < 8; ++e) {
          const bool act = aa[e] > 0;
          byte |= act ? (1u << e) : 0u;
          const bool pos = (ri.x + cx[e]) >= 0.f;
          accP[e] += (act && pos) ? ri.y : 0.f;
          accN[e] += (act && !pos) ? ri.z : 0.f;
        }
        bp[(size_t)(ir + u) * (NN / 8)] = (uchar)byte;
      }
    }
    float2* zp = zpart + (size_t)ic * NN + j0;
#pragma unroll
    for (int e = 0; e < 8; ++e) zp[e] = make_float2(accP[e], accN[e]);
  } else {
    // ---------------- GEMM path (R15 k1, minus score tail) ----------------
    typedef float4 hs4row_t[65];
    typedef float wtrow_t[132];
    hs4row_t* hs4 = (hs4row_t*)smem;                 // 16 x 65 float4 = 16640 B
    wtrow_t* wt = (wtrow_t*)(smem + 16640);          // 32 x 132 float = 16896 B
    const int bid = blockIdx.x - 512;
    const int j0 = bid * 16;
#pragma unroll
    for (int e = 0; e < 4; ++e) {
      const int i = t + 256 * e;
      const int row = i >> 6, q = i & 63;
      hs4[row][q] = *(const float4*)(h + (size_t)(j0 + row) * FI + 4 * q);
    }
    const int f4 = (t & 31) * 4;
    const int r0 = (t >> 5) * 2;
    float acc[2][4];
#pragma unroll
    for (int r = 0; r < 2; ++r)
#pragma unroll
      for (int e = 0; e < 4; ++e) acc[r][e] = 0.f;

    for (int kc = 0; kc < FI; kc += 32) {
      __syncthreads();
      {
        const int f = t >> 1, kb = (t & 1) * 16;
        const float* wsrc = W + (size_t)f * FI + kc + kb;
#pragma unroll
        for (int e = 0; e < 4; ++e) {
          const float4 wv = *(const float4*)(wsrc + 4 * e);
          wt[kb + 4 * e + 0][f] = wv.x;
          wt[kb + 4 * e + 1][f] = wv.y;
          wt[kb + 4 * e + 2][f] = wv.z;
          wt[kb + 4 * e + 3][f] = wv.w;
        }
      }
      __syncthreads();
#pragma unroll
      for (int kk = 0; kk < 8; ++kk) {
        float4 wv[4];
#pragma unroll
        for (int i = 0; i < 4; ++i) wv[i] = *(const float4*)&wt[4 * kk + i][f4];
        float4 hv[2];
#pragma unroll
        for (int r = 0; r < 2; ++r) hv[r] = hs4[r0 + r][(kc >> 2) + kk];
#pragma unroll
        for (int r = 0; r < 2; ++r) {
          acc[r][0] += hv[r].x * wv[0].x + hv[r].y * wv[1].x + hv[r].z * wv[2].x + hv[r].w * wv[3].x;
          acc[r][1] += hv[r].x * wv[0].y + hv[r].y * wv[1].y + hv[r].z * wv[2].y + hv[r].w * wv[3].y;
          acc[r][2] += hv[r].x * wv[0].z + hv[r].y * wv[1].z + hv[r].z * wv[2].z + hv[r].w * wv[3].z;
          acc[r][3] += hv[r].x * wv[0].w + hv[r].y * wv[1].w + hv[r].z * wv[2].w + hv[r].w * wv[3].w;
        }
      }
    }
    const float4 bv = *(const float4*)&bias[f4];
#pragma unroll
    for (int r = 0; r < 2; ++r) {
      float4 o;
      o.x = acc[r][0] + bv.x;
      o.y = acc[r][1] + bv.y;
      o.z = acc[r][2] + bv.z;
      o.w = acc[r][3] + bv.w;
      *(float4*)&Wh[(size_t)(j0 + r0 + r) * FO + f4] = o;
    }
  }
}

// ---------------------------------------------------------------------------
// K3: Z_j from 128 partials; emit Wfrag in MFMA-B-fragment-major layout.
// Empty cols -> corr[f] (uniform softmax fix).
// ---------------------------------------------------------------------------
__global__ __launch_bounds__(256) void k3_scale(const float* __restrict__ Wh,
                                                const float4* __restrict__ c4,
                                                const float2* __restrict__ zpart,
                                                _Float16* __restrict__ Wfrag,
                                                float* __restrict__ corr) {
  __shared__ float rz[64];
  __shared__ int emp[64];
  __shared__ float2 psum[256];
  __shared__ __align__(16) _Float16 tile[FO * 64];
  const int t = threadIdx.x;
  const int j0 = blockIdx.x * 64;
  {
    const int jl = t & 63, q = t >> 6;
    float p = 0.f, n = 0.f;
    for (int ic = q * 32; ic < q * 32 + 32; ++ic) {
      const float2 z = zpart[(size_t)ic * NN + j0 + jl];
      p += z.x;
      n += z.y;
    }
    psum[t] = make_float2(p, n);
  }
  __syncthreads();
  if (t < 64) {
    const float p = psum[t].x + psum[64 + t].x + psum[128 + t].x + psum[192 + t].x;
    const float n = psum[t].y + psum[64 + t].y + psum[128 + t].y + psum[192 + t].y;
    const float4 cj = c4[j0 + t];
    const float Z = cj.y * p + cj.z * n;
    rz[t] = (Z > 0.f) ? 1.f / Z : 0.f;
    emp[t] = (Z > 0.f) ? 0 : 1;
  }
  __syncthreads();
  const int f = t & 127, half = t >> 7;
  const unsigned swf = (unsigned)((f & 7) << 4);
  for (int r = half; r < 64; r += 2) {
    const float v = Wh[(size_t)(j0 + r) * FO + f];
    *(_Float16*)((char*)tile + f * 128 + (((unsigned)(r * 2)) ^ swf)) =
        (_Float16)(v * rz[r]);
    if (emp[r]) atomicAdd(&corr[f], v * (1.f / 8192.f));
  }
  __syncthreads();
#pragma unroll
  for (int q = 0; q < 4; ++q) {
    const int G = t + 256 * q;
    const int kcfb = G >> 6, gl = G & 63;
    const int kc = kcfb >> 3, fb = kcfb & 7;
    const int gf = fb * 16 + (gl & 15);
    const int jloc = kc * 32 + (gl >> 4) * 8;
    const f16x8 v = *(const f16x8*)((const char*)tile + gf * 128 +
                                    (((unsigned)(jloc * 2)) ^ ((unsigned)((gf & 7) << 4))));
    ((f16x8*)Wfrag)[(size_t)(((j0 >> 5) + kc) * 8 + fb) * 64 + gl] = v;
  }
}

// ---------------------------------------------------------------------------
// K4 (R11 champion): partial h' = P~ @ (Wh/Z) -> part[kq].
// BM=32, 256 thr = 4 waves (1x4), ksplit=4 (2048 cols, 32 steps of 64).
// ---------------------------------------------------------------------------
#define BARRIER_LDS()                                          \
  do {                                                         \
    __builtin_amdgcn_sched_barrier(0);                         \
    asm volatile("s_waitcnt lgkmcnt(0)" ::: "memory");         \
    __builtin_amdgcn_s_barrier();                              \
    __builtin_amdgcn_sched_barrier(0);                         \
  } while (0)

__global__ __launch_bounds__(256) void k4_main(const uchar* __restrict__ bitsB,
                                               const float2* __restrict__ r2,
                                               const _Float16* __restrict__ ey16,
                                               const _Float16* __restrict__ ez16,
                                               const _Float16* __restrict__ Wfrag,
                                               float* __restrict__ part) {
  __shared__ __align__(16) _Float16 P[2][32 * 64];
  __shared__ uint32 lut[256][4];
  const int t = threadIdx.x;
  const int rowtile = blockIdx.x >> 2;
  const int kq = blockIdx.x & 3;
  const int rowbase = rowtile * 32;
  const int koff = kq * 2048;

  {
#pragma unroll
    for (int p = 0; p < 4; ++p) {
      const uint32 lo = ((t >> (2 * p)) & 1) ? 0x0000FFFFu : 0u;
      const uint32 hi = ((t >> (2 * p + 1)) & 1) ? 0xFFFF0000u : 0u;
      lut[t][p] = lo | hi;
    }
  }

  const int pr = t >> 3, jq = t & 7;
  const float2 rr = r2[rowbase + pr];
  const f16x2 rx2 = {(_Float16)rr.x, (_Float16)rr.x};
  const f16x2 ry2 = {(_Float16)rr.y, (_Float16)rr.y};
  const uchar* bp = bitsB + (size_t)(rowbase + pr) * (NN / 8) + (koff >> 3) + jq;
  const _Float16* eyp = ey16 + koff + jq * 8;
  const _Float16* ezp = ez16 + koff + jq * 8;
  char* const pdst0 = (char*)&P[0][0] + pr * 128 + (((unsigned)(jq * 16)) ^ ((unsigned)((pr & 7) << 4)));
  char* const pdst1 = (char*)&P[1][0] + pr * 128 + (((unsigned)(jq * 16)) ^ ((unsigned)((pr & 7) << 4)));

  const int lane = t & 63, wc = t >> 6;
  const int kgrp = lane >> 4, l15 = lane & 15;
  const unsigned asw = (unsigned)((l15 & 7) << 4);
  const int ar0 = l15 * 128;
  const int ar1 = ar0 + 16 * 128;

  f32x4 acc00 = {0.f, 0.f, 0.f, 0.f}, acc01 = {0.f, 0.f, 0.f, 0.f};
  f32x4 acc10 = {0.f, 0.f, 0.f, 0.f}, acc11 = {0.f, 0.f, 0.f, 0.f};

  uchar mb0, mb1;
  uint4 ey0, ez0, ey1, ez1;
  f16x8 B000, B001, B010, B011, B100, B101, B110, B111;

#define LOADALL(S, MB, EY, EZ, Bq00, Bq01, Bq10, Bq11)                              \
  do {                                                                              \
    MB = bp[(S) * 8];                                                               \
    EY = *(const uint4*)(eyp + (S) * 64);                                           \
    EZ = *(const uint4*)(ezp + (S) * 64);                                           \
    const _Float16* _b = Wfrag + ((size_t)((kq * 64 + (S) * 2) * 8 + wc * 2) * 64 + lane) * 8; \
    Bq00 = *(const f16x8*)(_b);                                                     \
    Bq01 = *(const f16x8*)(_b + 512);                                               \
    Bq10 = *(const f16x8*)(_b + 4096);                                              \
    Bq11 = *(const f16x8*)(_b + 4096 + 512);                                        \
  } while (0)

#define PGEN(DST, MB, EY, EZ)                                                        \
  do {                                                                               \
    const uint4 _m = *(const uint4*)(&lut[MB][0]);                                   \
    const uint32 _eys[4] = {EY.x, EY.y, EY.z, EY.w};                                 \
    const uint32 _ezs[4] = {EZ.x, EZ.y, EZ.z, EZ.w};                                 \
    const uint32 _ms[4] = {_m.x, _m.y, _m.z, _m.w};                                  \
    uint32 _o[4];                                                                    \
    _Pragma("unroll") for (int _p = 0; _p < 4; ++_p) {                               \
      const f16x2 _a = __builtin_bit_cast(f16x2, _eys[_p]) * rx2;                    \
      const f16x2 _b2 = __builtin_bit_cast(f16x2, _ezs[_p]) * ry2;                   \
      const f16x2 _mx = __builtin_elementwise_max(_a, _b2);                          \
      _o[_p] = __builtin_bit_cast(uint32, _mx) & _ms[_p];                            \
    }                                                                                \
    uint4 _st; _st.x = _o[0]; _st.y = _o[1]; _st.z = _o[2]; _st.w = _o[3];           \
    *(uint4*)(DST) = _st;                                                            \
  } while (0)

#define DO_MFMA(BUF, Bq00, Bq01, Bq10, Bq11)                                        \
  do {                                                                              \
    const char* _Pb = (const char*)&P[BUF][0];                                      \
    const f16x8 a00 = *(const f16x8*)(_Pb + ar0 + ((((unsigned)(kgrp * 16))) ^ asw));        \
    const f16x8 a01 = *(const f16x8*)(_Pb + ar0 + (((unsigned)(64 + kgrp * 16)) ^ asw));     \
    const f16x8 a10 = *(const f16x8*)(_Pb + ar1 + ((((unsigned)(kgrp * 16))) ^ asw));        \
    const f16x8 a11 = *(const f16x8*)(_Pb + ar1 + (((unsigned)(64 + kgrp * 16)) ^ asw));     \
    __builtin_amdgcn_s_setprio(1);                                                  \
    acc00 = __builtin_amdgcn_mfma_f32_16x16x32_f16(a00, Bq00, acc00, 0, 0, 0);      \
    acc01 = __builtin_amdgcn_mfma_f32_16x16x32_f16(a00, Bq01, acc01, 0, 0, 0);      \
    acc10 = __builtin_amdgcn_mfma_f32_16x16x32_f16(a10, Bq00, acc10, 0, 0, 0);      \
    acc11 = __builtin_amdgcn_mfma_f32_16x16x32_f16(a10, Bq01, acc11, 0, 0, 0);      \
    acc00 = __builtin_amdgcn_mfma_f32_16x16x32_f16(a01, Bq10, acc00, 0, 0, 0);      \
    acc01 = __builtin_amdgcn_mfma_f32_16x16x32_f16(a01, Bq11, acc01, 0, 0, 0);      \
    acc10 = __builtin_amdgcn_mfma_f32_16x16x32_f16(a11, Bq10, acc10, 0, 0, 0);      \
    acc11 = __builtin_amdgcn_mfma_f32_16x16x32_f16(a11, Bq11, acc11, 0, 0, 0);      \
    __builtin_amdgcn_s_setprio(0);                                                  \
  } while (0)

  // ---- prologue (sync covers lut writes before first PGEN lut read)
  LOADALL(0, mb0, ey0, ez0, B000, B001, B010, B011);
  LOADALL(1, mb1, ey1, ez1, B100, B101, B110, B111);
  __syncthreads();
  PGEN(pdst0, mb0, ey0, ez0);
  BARRIER_LDS();

  for (int s = 0; s < 32; s += 2) {
    PGEN(pdst1, mb1, ey1, ez1);                       // P for step s+1
    DO_MFMA(0, B000, B001, B010, B011);               // step s
    if (s + 2 < 32) LOADALL(s + 2, mb0, ey0, ez0, B000, B001, B010, B011);
    BARRIER_LDS();
    DO_MFMA(1, B100, B101, B110, B111);               // step s+1
    if (s + 2 < 32) PGEN(pdst0, mb0, ey0, ez0);       // P for step s+2
    if (s + 3 < 32) LOADALL(s + 3, mb1, ey1, ez1, B100, B101, B110, B111);
    BARRIER_LDS();
  }

#undef LOADALL
#undef PGEN
#undef DO_MFMA

  const int orow = rowbase + kgrp * 4;
  const int ocol = wc * 32 + l15;
  float* aP = part + (size_t)kq * NN * FO + (size_t)orow * FO + ocol;
#pragma unroll
  for (int r = 0; r < 4; ++r) {
    aP[(size_t)r * FO] = acc00[r];
    aP[(size_t)r * FO + 16] = acc01[r];
    aP[(size_t)(16 + r) * FO] = acc10[r];
    aP[(size_t)(16 + r) * FO + 16] = acc11[r];
  }
}

// ---------------------------------------------------------------------------
// K5: out = elu(sum_q part[q] + corr), 4 partials
// ---------------------------------------------------------------------------
__global__ __launch_bounds__(256) void k5_fin(const float* __restrict__ part,
                                              const float* __restrict__ corr,
                                              float* __restrict__ out) {
  const int idx = blockIdx.x * 256 + threadIdx.x;
  const float4 p0 = ((const float4*)part)[idx];
  const float4 p1 = ((const float4*)(part + (size_t)NN * FO))[idx];
  const float4 p2 = ((const float4*)(part + (size_t)2 * NN * FO))[idx];
  const float4 p3 = ((const float4*)(part + (size_t)3 * NN * FO))[idx];
  const float4 c = ((const float4*)corr)[idx & 31];
  float4 v;
  v.x = p0.x + p1.x + p2.x + p3.x + c.x;
  v.y = p0.y + p1.y + p2.y + p3.y + c.y;
  v.z = p0.z + p1.z + p2.z + p3.z + c.z;
  v.w = p0.w + p1.w + p2.w + p3.w + c.w;
  v.x = (v.x > 0.f) ? v.x : (expf(v.x) - 1.f);
  v.y = (v.y > 0.f) ? v.y : (expf(v.y) - 1.f);
  v.z = (v.z > 0.f) ? v.z : (expf(v.z) - 1.f);
  v.w = (v.w > 0.f) ? v.w : (expf(v.w) - 1.f);
  ((float4*)out)[idx] = v;
}

// ---------------------------------------------------------------------------
extern "C" void kernel_launch(void* const* d_in, const int* in_sizes, int n_in,
                              void* d_out, int out_size, void* d_ws, size_t ws_size,
                              hipStream_t stream) {
  const float* h = (const float*)d_in[0];
  const int* adj = (const int*)d_in[1];
  const float* W = (const float*)d_in[2];
  const float* b = (const float*)d_in[3];
  const float* a = (const float*)d_in[4];
  float* out = (float*)d_out;
  char* ws = (char*)d_ws;

  float* Wh = (float*)(ws + 0);                                   // 4 MB  [mega..k3]
  _Float16* Wfrag = (_Float16*)(ws + 0x400000);                   // 2 MB  [k3..k4]
  uchar* bits = (uchar*)(ws + 0x600000);                          // 8 MB  [mega..k4]
  float2* zpart = (float2*)(ws + 0xE00000);                       // 8 MB  [mega..k3]
  float4* r4 = (float4*)(ws + 0x1600000);                         // 128 KB
  float4* c4 = (float4*)(ws + 0x1620000);                         // 128 KB
  float2* r2 = (float2*)(ws + 0x1640000);                         // 64 KB
  _Float16* ey16 = (_Float16*)(ws + 0x1650000);                   // 16 KB
  _Float16* ez16 = (_Float16*)(ws + 0x1654000);                   // 16 KB
  float* s2x = (float*)(ws + 0x1658000);                          // 32 KB
  float* corr = (float*)(ws + 0x1660000);                         // 512 B
  float* part = (float*)(ws + 0x1700000);                         // 16 MB [k4..k5]

  k1s_scores<<<NN / 32, 256, 0, stream>>>(h, W, b, a, r4, c4, r2, ey16, ez16, s2x, corr);
  mega<<<1024, 256, 0, stream>>>(adj, h, W, b, r4, s2x, bits, zpart, Wh);
  k3_scale<<<NN / 64, 256, 0, stream>>>(Wh, c4, zpart, Wfrag, corr);
  k4_main<<<1024, 256, 0, stream>>>(bits, r2, ey16, ez16, Wfrag, part);
  k5_fin<<<(NN * FO / 4) / 256, 256, 0, stream>>>(part, corr, out);
}